// Round 5
// baseline (416.318 us; speedup 1.0000x reference)
//
#include <hip/hip_runtime.h>

#define Tsz 512
#define Hsz 256

typedef __attribute__((ext_vector_type(8))) short short8;
typedef __attribute__((ext_vector_type(4))) short short4v;
typedef __attribute__((ext_vector_type(4))) float f32x4;

static __device__ __forceinline__ unsigned short f2bf(float f) {
    union { float f; unsigned int i; } v; v.f = f;
    unsigned int r = v.i + 0x7fffu + ((v.i >> 16) & 1u);   // RNE
    return (unsigned short)(r >> 16);
}
static __device__ __forceinline__ short8 ld8f(const float* p) {
    const float4* q = (const float4*)p;
    float4 a = q[0], b = q[1];
    short8 v;
    v[0] = (short)f2bf(a.x); v[1] = (short)f2bf(a.y); v[2] = (short)f2bf(a.z); v[3] = (short)f2bf(a.w);
    v[4] = (short)f2bf(b.x); v[5] = (short)f2bf(b.y); v[6] = (short)f2bf(b.z); v[7] = (short)f2bf(b.w);
    return v;
}
static __device__ __forceinline__ float sigm(float z) {
    return __builtin_amdgcn_rcpf(1.f + __expf(-z));
}

// Fused MGU, role-split: 16 waves (1024 thr), 1 block/CU, 1 batch/block.
// Waves 0-7: scan only (h-matvec, N=32 each). Waves 8-15: gate GEMM drip +
// x staging + gate epilogue. Weight frags SHARED virtual regs (wf = Wh or Wx
// per wave) so both paths' live sets fit the 128-VGPR/4-wave-per-SIMD cap.
__global__ __launch_bounds__(1024, 1) void mgu_fused(
    const float* __restrict__ x,   const float* __restrict__ Wxw,
    const float* __restrict__ Wxb, const float* __restrict__ Whw,
    const float* __restrict__ Whb, float* __restrict__ out)
{
    __shared__ __align__(16) unsigned short xs[2][16 * 256];  // bf16 x chunks, swizzled
    __shared__ __align__(16) float          gs[2][16 * 256];  // f32 gates
    __shared__ __align__(16) unsigned short hbuf[2][256];     // bf16 h double buffer

    const int tid  = threadIdx.x;
    const int b    = blockIdx.x;
    const int l    = tid & 63;
    const int w    = tid >> 6;        // 0..15
    const int wg   = w & 7;
    const int lo16 = l & 15;
    const int hi   = l >> 4;
    const bool is_scan = (w < 8);

    // Unified weight fragments: scan waves hold Wh, gate waves hold Wx.
    // B[k][n] = W[n][k]; lane n = wg*32+nt*16+lo16, k = ks*32+hi*8..+7
    const float* Wsel = is_scan ? Whw : Wxw;
    const float* Bsel = is_scan ? Whb : Wxb;
    short8 wf[2][8];
    float  bb[2];
#pragma unroll
    for (int nt = 0; nt < 2; ++nt) {
        int n = wg * 32 + nt * 16 + lo16;
        bb[nt] = Bsel[n];
#pragma unroll
        for (int ks = 0; ks < 8; ++ks)
            wf[nt][ks] = ld8f(Wsel + (size_t)n * 256 + ks * 32 + hi * 8);
    }

    const float* xrow = x   + (size_t)b * Tsz * Hsz;
    float*       orow = out + (size_t)b * Tsz * Hsz;

    // ---- prologue: stage x chunks 0,1 (bf16, 16B-chunk XOR swizzle) ----
#pragma unroll
    for (int i = 0; i < 2; ++i) {
        int idx = tid + i * 1024;         // 0..2047
        int m   = idx >> 6;               // global row 0..31
        int j   = idx & 63;               // float4 index in row
        float4 v = *(const float4*)(xrow + (size_t)m * 256 + j * 4);
        short4v s4;
        s4[0] = (short)f2bf(v.x); s4[1] = (short)f2bf(v.y);
        s4[2] = (short)f2bf(v.z); s4[3] = (short)f2bf(v.w);
        int r   = m & 15;
        int byt = r * 512 + (((j >> 1) ^ (r & 7)) << 4) + (j & 1) * 8;
        *(short4v*)((char*)xs[m >> 4] + byt) = s4;
    }
    if (tid < 256) hbuf[0][tid] = 0;
    __syncthreads();

    // ---- gates chunk 0 (gate waves, full pass: 16 MFMAs/wave) ----
    if (!is_scan) {
        f32x4 ag0 = {0.f, 0.f, 0.f, 0.f}, ag1 = {0.f, 0.f, 0.f, 0.f};
#pragma unroll
        for (int ks = 0; ks < 8; ++ks) {
            short8 a = *(const short8*)((const char*)xs[0]
                         + lo16 * 512 + (((ks * 4 + hi) ^ (lo16 & 7)) << 4));
            ag0 = __builtin_amdgcn_mfma_f32_16x16x32_bf16(a, wf[0][ks], ag0, 0, 0, 0);
            ag1 = __builtin_amdgcn_mfma_f32_16x16x32_bf16(a, wf[1][ks], ag1, 0, 0, 0);
        }
#pragma unroll
        for (int r = 0; r < 4; ++r) {
            gs[0][(hi * 4 + r) * 256 + wg * 32 + lo16]      = sigm(ag0[r] + bb[0]);
            gs[0][(hi * 4 + r) * 256 + wg * 32 + 16 + lo16] = sigm(ag1[r] + bb[1]);
        }
    }

    float  hreg = 0.f;
    float4 xcarry;
    if (w == 8) xcarry = *(const float4*)(xrow + (size_t)32 * 256 + l * 4);

    f32x4 accg0 = {0.f, 0.f, 0.f, 0.f}, accg1 = {0.f, 0.f, 0.f, 0.f};
    short8 afg;
    int p = 0;

    for (int c = 0; c < 32; ++c) {
        unsigned short* xs_rd = xs[(c & 1) ^ 1];   // x of chunk c+1 (drip source)
        unsigned short* xs_wr = xs[c & 1];         // staging x of chunk c+2
        const float*    gs_rd = gs[c & 1];         // gates of chunk c
        float*          gs_wr = gs[(c & 1) ^ 1];   // gates of chunk c+1
#pragma unroll
        for (int s = 0; s < 16; ++s) {
            const int t = c * 16 + s;
            __syncthreads();                        // h[t-1], gates, staged x visible

            if (is_scan) {
                // ---- scan step: minimal critical path ----
                __builtin_amdgcn_s_setprio(1);
                f32x4 a0lo = {bb[0], 0.f, 0.f, 0.f}, a0hi = {0.f, 0.f, 0.f, 0.f};
                f32x4 a1lo = {bb[1], 0.f, 0.f, 0.f}, a1hi = {0.f, 0.f, 0.f, 0.f};
#pragma unroll
                for (int ks = 0; ks < 4; ++ks) {
                    short8 afA = *(const short8*)(const void*)(&hbuf[p][ks * 32 + hi * 8]);
                    short8 afB = *(const short8*)(const void*)(&hbuf[p][(ks + 4) * 32 + hi * 8]);
                    a0lo = __builtin_amdgcn_mfma_f32_16x16x32_bf16(afA, wf[0][ks],     a0lo, 0, 0, 0);
                    a1lo = __builtin_amdgcn_mfma_f32_16x16x32_bf16(afA, wf[1][ks],     a1lo, 0, 0, 0);
                    a0hi = __builtin_amdgcn_mfma_f32_16x16x32_bf16(afB, wf[0][ks + 4], a0hi, 0, 0, 0);
                    a1hi = __builtin_amdgcn_mfma_f32_16x16x32_bf16(afB, wf[1][ks + 4], a1hi, 0, 0, 0);
                }
                __builtin_amdgcn_s_setprio(0);

                float zz = (hi == 0) ? (a0lo[0] + a0hi[0]) : (a1lo[0] + a1hi[0]);
                zz = fminf(fmaxf(zz, -15.f), 15.f);
                float ex = __expf(2.f * zz);
                float th = (ex - 1.f) * __builtin_amdgcn_rcpf(ex + 1.f);
                if (hi < 2) {
                    int   n  = wg * 32 + hi * 16 + lo16;
                    float g  = gs_rd[s * 256 + n];
                    float hn = g * hreg + (1.f - g) * th;
                    hreg = hn;
                    hbuf[p ^ 1][n] = f2bf(hn);
                    orow[(size_t)t * 256 + n] = hn;
                }
            } else {
                // ---- gate/staging step ----
                if ((s & 1) == 0)
                    afg = *(const short8*)((const char*)xs_rd
                            + lo16 * 512 + ((((s >> 1) * 4 + hi) ^ (lo16 & 7)) << 4));
                if ((s & 1) == 0)
                    accg0 = __builtin_amdgcn_mfma_f32_16x16x32_bf16(afg, wf[0][s >> 1], accg0, 0, 0, 0);
                else
                    accg1 = __builtin_amdgcn_mfma_f32_16x16x32_bf16(afg, wf[1][s >> 1], accg1, 0, 0, 0);

                if (w == 8) {   // stage x row t+32 (chunk c+2, row s)
                    short4v s4;
                    s4[0] = (short)f2bf(xcarry.x); s4[1] = (short)f2bf(xcarry.y);
                    s4[2] = (short)f2bf(xcarry.z); s4[3] = (short)f2bf(xcarry.w);
                    int byt = s * 512 + (((l >> 1) ^ (s & 7)) << 4) + (l & 1) * 8;
                    *(short4v*)((char*)xs_wr + byt) = s4;
                    int nr = t + 33; if (nr > Tsz - 1) nr = Tsz - 1;
                    xcarry = *(const float4*)(xrow + (size_t)nr * 256 + l * 4);
                }

                if (s == 15) {   // finish gates chunk c+1
#pragma unroll
                    for (int r = 0; r < 4; ++r) {
                        gs_wr[(hi * 4 + r) * 256 + wg * 32 + lo16]      = sigm(accg0[r] + bb[0]);
                        gs_wr[(hi * 4 + r) * 256 + wg * 32 + 16 + lo16] = sigm(accg1[r] + bb[1]);
                    }
                    f32x4 z = {0.f, 0.f, 0.f, 0.f}; accg0 = z; accg1 = z;
                }
            }
            p ^= 1;
        }
    }
}

extern "C" void kernel_launch(void* const* d_in, const int* in_sizes, int n_in,
                              void* d_out, int out_size, void* d_ws, size_t ws_size,
                              hipStream_t stream) {
    const float* x   = (const float*)d_in[0];
    const float* Wxw = (const float*)d_in[1];
    const float* Wxb = (const float*)d_in[2];
    const float* Whw = (const float*)d_in[3];
    const float* Whb = (const float*)d_in[4];

    mgu_fused<<<dim3(256), dim3(1024), 0, stream>>>(x, Wxw, Wxb, Whw, Whb, (float*)d_out);
}

// Round 6
// 277.445 us; speedup vs baseline: 1.5005x; 1.5005x over previous
//
#include <hip/hip_runtime.h>

#define Tsz 512
#define Hsz 256

typedef __attribute__((ext_vector_type(8))) short short8;
typedef __attribute__((ext_vector_type(4))) short short4v;
typedef __attribute__((ext_vector_type(4))) float f32x4;

static __device__ __forceinline__ unsigned short f2bf(float f) {
    union { float f; unsigned int i; } v; v.f = f;
    unsigned int r = v.i + 0x7fffu + ((v.i >> 16) & 1u);   // RNE
    return (unsigned short)(r >> 16);
}
static __device__ __forceinline__ short8 ld8f(const float* p) {
    const float4* q = (const float4*)p;
    float4 a = q[0], b = q[1];
    short8 v;
    v[0] = (short)f2bf(a.x); v[1] = (short)f2bf(a.y); v[2] = (short)f2bf(a.z); v[3] = (short)f2bf(a.w);
    v[4] = (short)f2bf(b.x); v[5] = (short)f2bf(b.y); v[6] = (short)f2bf(b.z); v[7] = (short)f2bf(b.w);
    return v;
}
static __device__ __forceinline__ float sigm(float z) {
    return __builtin_amdgcn_rcpf(1.f + __expf(-z));
}
// Barrier with LDS-only drain: global loads/stores (private or write-only)
// are NOT forced to complete — removes HBM/L2 latency from the barrier path.
static __device__ __forceinline__ void block_sync_lds() {
    asm volatile("s_waitcnt lgkmcnt(0)" ::: "memory");
    __builtin_amdgcn_s_barrier();
}

// Fused MGU, 8 waves/block, 1 block/CU (grid=256). Wave w owns cols [w*32,w*32+32).
// Wh+Wx register-resident as MFMA B-frags. launch_bounds(512,2): 256-VGPR cap,
// no spill (round-4 cap of 128 caused ~26MB scratch traffic).
__global__ __launch_bounds__(512, 2) void mgu_fused(
    const float* __restrict__ x,   const float* __restrict__ Wxw,
    const float* __restrict__ Wxb, const float* __restrict__ Whw,
    const float* __restrict__ Whb, float* __restrict__ out)
{
    __shared__ __align__(16) unsigned short xs[2][16 * 256];  // bf16 x chunks, swizzled
    __shared__ __align__(16) float          gs[2][16 * 256];  // f32 gates
    __shared__ __align__(16) unsigned short hbuf[2][256];     // bf16 h double buffer

    const int tid  = threadIdx.x;
    const int b    = blockIdx.x;
    const int l    = tid & 63;
    const int w    = tid >> 6;       // 0..7
    const int lo16 = l & 15;
    const int hi   = l >> 4;

    // B-frags: B[k][n] = W[n][k]; lane holds n = w*32+nt*16+lo16, k = ks*32+hi*8..+7
    short8 wfh[2][8], wfx[2][8];
    float  bh[2], bx[2];
#pragma unroll
    for (int nt = 0; nt < 2; ++nt) {
        int n = w * 32 + nt * 16 + lo16;
        bh[nt] = Whb[n];
        bx[nt] = Wxb[n];
#pragma unroll
        for (int ks = 0; ks < 8; ++ks) {
            wfh[nt][ks] = ld8f(Whw + (size_t)n * 256 + ks * 32 + hi * 8);
            wfx[nt][ks] = ld8f(Wxw + (size_t)n * 256 + ks * 32 + hi * 8);
        }
    }

    const float* xrow = x   + (size_t)b * Tsz * Hsz;
    float*       orow = out + (size_t)b * Tsz * Hsz;

    // ---- prologue: stage x chunks 0,1 (bf16, 16B-chunk XOR swizzle) ----
#pragma unroll
    for (int i = 0; i < 4; ++i) {
        int idx = tid + i * 512;          // 0..2047
        int m   = idx >> 6;               // global row 0..31
        int j   = idx & 63;               // float4 index in row
        float4 v = *(const float4*)(xrow + (size_t)m * 256 + j * 4);
        short4v s4;
        s4[0] = (short)f2bf(v.x); s4[1] = (short)f2bf(v.y);
        s4[2] = (short)f2bf(v.z); s4[3] = (short)f2bf(v.w);
        int r   = m & 15;
        int byt = r * 512 + (((j >> 1) ^ (r & 7)) << 4) + (j & 1) * 8;
        *(short4v*)((char*)xs[m >> 4] + byt) = s4;
    }
    if (tid < 256) hbuf[0][tid] = 0;
    __syncthreads();

    // ---- gates chunk 0 (full pass: 16 MFMAs/wave) ----
    {
        f32x4 ag0 = {0.f, 0.f, 0.f, 0.f}, ag1 = {0.f, 0.f, 0.f, 0.f};
#pragma unroll
        for (int ks = 0; ks < 8; ++ks) {
            short8 afg = *(const short8*)((const char*)xs[0]
                           + lo16 * 512 + (((ks * 4 + hi) ^ (lo16 & 7)) << 4));
            ag0 = __builtin_amdgcn_mfma_f32_16x16x32_bf16(afg, wfx[0][ks], ag0, 0, 0, 0);
            ag1 = __builtin_amdgcn_mfma_f32_16x16x32_bf16(afg, wfx[1][ks], ag1, 0, 0, 0);
        }
#pragma unroll
        for (int r = 0; r < 4; ++r) {
            gs[0][(hi * 4 + r) * 256 + w * 32 + lo16]      = sigm(ag0[r] + bx[0]);
            gs[0][(hi * 4 + r) * 256 + w * 32 + 16 + lo16] = sigm(ag1[r] + bx[1]);
        }
    }

    float  hreg = 0.f;
    float4 xcarry;
    if (tid < 64) xcarry = *(const float4*)(xrow + (size_t)32 * 256 + tid * 4);

    f32x4 accg[2];
    { f32x4 z = {0.f, 0.f, 0.f, 0.f}; accg[0] = z; accg[1] = z; }

    int p = 0;
    for (int c = 0; c < 32; ++c) {
        unsigned short* xs_rd = xs[(c & 1) ^ 1];   // x of chunk c+1 (drip source)
        unsigned short* xs_wr = xs[c & 1];         // staging x of chunk c+2
        const float*    gs_rd = gs[c & 1];         // gates of chunk c
        float*          gs_wr = gs[(c & 1) ^ 1];   // gates of chunk c+1
        short8 afg;
#pragma unroll
        for (int s = 0; s < 16; ++s) {
            const int t = c * 16 + s;
            block_sync_lds();                       // h[t-1], gates, staged x visible

            // hoist gate read (independent of h) off the critical tail
            const int n_ep = w * 32 + (hi & 1) * 16 + lo16;   // valid for all, used by hi<2
            float g = gs_rd[s * 256 + n_ep];

            // A frags from h broadcast (16 identical rows)
            short8 afh[8];
#pragma unroll
            for (int ks = 0; ks < 8; ++ks)
                afh[ks] = *(const short8*)(const void*)(&hbuf[p][ks * 32 + hi * 8]);

            // h-matvec: 16 MFMAs/wave, 4 independent chains of 4 (split-K)
            f32x4 a0lo = {bh[0], 0.f, 0.f, 0.f}, a0hi = {0.f, 0.f, 0.f, 0.f};
            f32x4 a1lo = {bh[1], 0.f, 0.f, 0.f}, a1hi = {0.f, 0.f, 0.f, 0.f};
#pragma unroll
            for (int ks = 0; ks < 4; ++ks) {
                a0lo = __builtin_amdgcn_mfma_f32_16x16x32_bf16(afh[ks],     wfh[0][ks],     a0lo, 0, 0, 0);
                a1lo = __builtin_amdgcn_mfma_f32_16x16x32_bf16(afh[ks],     wfh[1][ks],     a1lo, 0, 0, 0);
                a0hi = __builtin_amdgcn_mfma_f32_16x16x32_bf16(afh[ks + 4], wfh[0][ks + 4], a0hi, 0, 0, 0);
                a1hi = __builtin_amdgcn_mfma_f32_16x16x32_bf16(afh[ks + 4], wfh[1][ks + 4], a1hi, 0, 0, 0);
            }

            // gate drip for chunk c+1: 1 MFMA/step (nt = s&1, ks = s>>1)
            if ((s & 1) == 0)
                afg = *(const short8*)((const char*)xs_rd
                        + lo16 * 512 + ((((s >> 1) * 4 + hi) ^ (lo16 & 7)) << 4));
            accg[s & 1] = __builtin_amdgcn_mfma_f32_16x16x32_bf16(afg, wfx[s & 1][s >> 1], accg[s & 1], 0, 0, 0);

            // stage x row t+32 (chunk c+2, row s): 64 threads, b64 writes.
            // xcarry load rides across barriers now (no vmcnt drain).
            if (tid < 64) {
                short4v s4;
                s4[0] = (short)f2bf(xcarry.x); s4[1] = (short)f2bf(xcarry.y);
                s4[2] = (short)f2bf(xcarry.z); s4[3] = (short)f2bf(xcarry.w);
                int byt = s * 512 + (((tid >> 1) ^ (s & 7)) << 4) + (tid & 1) * 8;
                *(short4v*)((char*)xs_wr + byt) = s4;
                int nr = t + 33; if (nr > Tsz - 1) nr = Tsz - 1;
                xcarry = *(const float4*)(xrow + (size_t)nr * 256 + tid * 4);
            }

            // epilogue: col n = w*32 + hi*16 + lo16 owned by hi<2 threads
            float zz = (hi == 0) ? (a0lo[0] + a0hi[0]) : (a1lo[0] + a1hi[0]);
            zz = fminf(fmaxf(zz, -15.f), 15.f);
            float ex = __expf(2.f * zz);
            float th = (ex - 1.f) * __builtin_amdgcn_rcpf(ex + 1.f);
            if (hi < 2) {
                float hn = g * hreg + (1.f - g) * th;
                hreg = hn;
                hbuf[p ^ 1][n_ep] = f2bf(hn);
                orow[(size_t)t * 256 + n_ep] = hn;   // write-only: rides across barrier
            }

            if (s == 15) {   // finish gates chunk c+1
#pragma unroll
                for (int r = 0; r < 4; ++r) {
                    gs_wr[(hi * 4 + r) * 256 + w * 32 + lo16]      = sigm(accg[0][r] + bx[0]);
                    gs_wr[(hi * 4 + r) * 256 + w * 32 + 16 + lo16] = sigm(accg[1][r] + bx[1]);
                }
                f32x4 z = {0.f, 0.f, 0.f, 0.f}; accg[0] = z; accg[1] = z;
            }
            p ^= 1;
        }
    }
}

extern "C" void kernel_launch(void* const* d_in, const int* in_sizes, int n_in,
                              void* d_out, int out_size, void* d_ws, size_t ws_size,
                              hipStream_t stream) {
    const float* x   = (const float*)d_in[0];
    const float* Wxw = (const float*)d_in[1];
    const float* Wxb = (const float*)d_in[2];
    const float* Whw = (const float*)d_in[3];
    const float* Whb = (const float*)d_in[4];

    mgu_fused<<<dim3(256), dim3(512), 0, stream>>>(x, Wxw, Wxb, Whw, Whb, (float*)d_out);
}